// Round 7
// baseline (180.784 us; speedup 1.0000x reference)
//
#include <hip/hip_runtime.h>
#include <math.h>

// Single-head causal attention, B=8 T=2048 E=1024 D=64, fp32 in/out.
// wtrans (W -> bf16 W^T) -> qkv (MFMA GEMM, 64 tok/block, 2-deep x pipeline)
// -> attn (flash attention, split-K, K/V register prefetch, DPP-free softmax).

#define B_   8
#define T_   2048
#define E_   1024
#define D_   64
#define BT_  (B_ * T_)

typedef __attribute__((ext_vector_type(8))) short s16x8;   // 8 x bf16
typedef __attribute__((ext_vector_type(4))) short s16x4;
typedef __attribute__((ext_vector_type(4))) float f32x4;

__device__ __forceinline__ short f2bf(float f) {
    union { float f; unsigned u; } a; a.f = f;
    unsigned r = a.u + 0x7fffu + ((a.u >> 16) & 1u);   // RNE
    return (short)(r >> 16);
}

#define MFMA16(a, b, c) __builtin_amdgcn_mfma_f32_16x16x32_bf16((a), (b), (c), 0, 0, 0)

// DPP cross-lane move within 16-lane rows (VALU pipe, not DS).
#define DPPF(x, ctrl) __builtin_bit_cast(float, \
    __builtin_amdgcn_update_dpp(0, __builtin_bit_cast(int, (x)), (ctrl), 0xF, 0xF, true))

__device__ __forceinline__ float rsum16(float x) {
    x += DPPF(x, 0xB1);     // quad_perm xor1
    x += DPPF(x, 0x4E);     // quad_perm xor2
    x += DPPF(x, 0x124);    // row_ror:4
    x += DPPF(x, 0x128);    // row_ror:8
    return x;
}

// ---------------------------------------------------------------------------
// Kernel 0: W[1024][64] x3 (fp32) -> Wt[192][1024] (bf16, K-major).
// ---------------------------------------------------------------------------
__global__ __launch_bounds__(256) void wtrans_kernel(
    const float* __restrict__ Wq, const float* __restrict__ Wk,
    const float* __restrict__ Wv, short* __restrict__ Wt)
{
    __shared__ float sT[64][65];
    const int sel = blockIdx.x >> 4;            // 0=q 1=k 2=v
    const int k0  = (blockIdx.x & 15) * 64;
    const float* W = sel == 0 ? Wq : (sel == 1 ? Wk : Wv);
    const int t  = threadIdx.x;
    const int kr = t >> 4, c4 = (t & 15) * 4;
    #pragma unroll
    for (int i = 0; i < 4; ++i) {
        float4 v = *(const float4*)&W[(size_t)(k0 + kr + i * 16) * D_ + c4];
        sT[kr + i * 16][c4 + 0] = v.x; sT[kr + i * 16][c4 + 1] = v.y;
        sT[kr + i * 16][c4 + 2] = v.z; sT[kr + i * 16][c4 + 3] = v.w;
    }
    __syncthreads();
    #pragma unroll
    for (int i = 0; i < 4; ++i) {
        int n  = (t >> 4) + i * 16;
        int kk = (t & 15) * 4;
        s16x4 o;
        o.x = f2bf(sT[kk + 0][n]); o.y = f2bf(sT[kk + 1][n]);
        o.z = f2bf(sT[kk + 2][n]); o.w = f2bf(sT[kk + 3][n]);
        *(s16x4*)&Wt[(size_t)(sel * 64 + n) * E_ + k0 + kk] = o;
    }
}

// ---------------------------------------------------------------------------
// Kernel 1: QKV projection. Block 256 = 4 waves, 64 tokens, grid 256.
// Each wave: 3 feature-tiles x 4 token-tiles (A-frag reused 4x; Wt read
// exactly once per block -> 98 MB L2 total). x loads pipelined 2 iters deep.
// ---------------------------------------------------------------------------
__global__ __launch_bounds__(256, 2) void qkv_kernel(
    const float* __restrict__ x, const short* __restrict__ Wt,
    const float* __restrict__ bq, const float* __restrict__ bk,
    const float* __restrict__ bv,
    short* __restrict__ Qg, short* __restrict__ Kg, short* __restrict__ VTg)
{
    __shared__ short sX[2][64 * 72];            // [buf][token][64+8 pad] bf16
    const int tid  = threadIdx.x;
    const int lane = tid & 63;
    const int w    = tid >> 6;
    const int l15  = lane & 15, quad = lane >> 4;
    const int t0   = blockIdx.x * 64;
    const int bb   = t0 >> 11;                  // batch (blocks don't straddle)

    const int srow = tid >> 2;                  // 0..63
    const int skc  = (tid & 3) * 16;            // 0,16,32,48 (shorts)
    const float* px = &x[(size_t)(t0 + srow) * E_ + skc];

    f32x4 acc[3][4];
    #pragma unroll
    for (int a = 0; a < 3; ++a)
        #pragma unroll
        for (int h = 0; h < 4; ++h)
            acc[a][h] = (f32x4){0.f, 0.f, 0.f, 0.f};

    float4 lda[4], ldb[4];
    #pragma unroll
    for (int i = 0; i < 4; ++i) lda[i] = *(const float4*)(px + i * 4);       // k0=0
    #pragma unroll
    for (int i = 0; i < 4; ++i) ldb[i] = *(const float4*)(px + 64 + i * 4);  // k0=64

    int buf = 0;
    for (int k0 = 0; k0 < E_; k0 += 64) {
        s16x8 pk0, pk1;
        pk0[0] = f2bf(lda[0].x); pk0[1] = f2bf(lda[0].y);
        pk0[2] = f2bf(lda[0].z); pk0[3] = f2bf(lda[0].w);
        pk0[4] = f2bf(lda[1].x); pk0[5] = f2bf(lda[1].y);
        pk0[6] = f2bf(lda[1].z); pk0[7] = f2bf(lda[1].w);
        pk1[0] = f2bf(lda[2].x); pk1[1] = f2bf(lda[2].y);
        pk1[2] = f2bf(lda[2].z); pk1[3] = f2bf(lda[2].w);
        pk1[4] = f2bf(lda[3].x); pk1[5] = f2bf(lda[3].y);
        pk1[6] = f2bf(lda[3].z); pk1[7] = f2bf(lda[3].w);
        *(s16x8*)&sX[buf][srow * 72 + skc]     = pk0;
        *(s16x8*)&sX[buf][srow * 72 + skc + 8] = pk1;
        __syncthreads();

        #pragma unroll
        for (int i = 0; i < 4; ++i) lda[i] = ldb[i];   // shift pipeline
        if (k0 + 128 < E_) {                           // issue iter k0+128
            const float* p2 = px + k0 + 128;
            #pragma unroll
            for (int i = 0; i < 4; ++i) ldb[i] = *(const float4*)(p2 + i * 4);
        }

        #pragma unroll
        for (int c = 0; c < 2; ++c) {
            s16x8 aw[3];
            #pragma unroll
            for (int t3 = 0; t3 < 3; ++t3)
                aw[t3] = *(const s16x8*)&Wt[(size_t)((w * 3 + t3) * 16 + l15) * E_
                                            + k0 + c * 32 + quad * 8];
            s16x8 bx[4];
            #pragma unroll
            for (int h = 0; h < 4; ++h)
                bx[h] = *(const s16x8*)&sX[buf][(h * 16 + l15) * 72 + c * 32 + quad * 8];
            #pragma unroll
            for (int t3 = 0; t3 < 3; ++t3)
                #pragma unroll
                for (int h = 0; h < 4; ++h)
                    acc[t3][h] = MFMA16(aw[t3], bx[h], acc[t3][h]);
        }
        buf ^= 1;
    }

    // epilogue: last reads hit sX[1]; sVT overlays sX[0] (64x72) — no overlap.
    short* sVT = &sX[0][0];

    #pragma unroll
    for (int t3 = 0; t3 < 3; ++t3) {
        const int nt = w * 3 + t3;
        const int fb = (nt & 3) * 16 + quad * 4;
        const float* bias = nt < 4 ? bq : (nt < 8 ? bk : bv);
        f32x4 bsv = *(const f32x4*)&bias[fb];
        #pragma unroll
        for (int h = 0; h < 4; ++h) {
            const int tok = t0 + h * 16 + l15;
            f32x4 v = acc[t3][h] + bsv;
            if (nt < 4) {
                v *= 0.125f;                    // fold 1/sqrt(64) into Q
                s16x4 o = { f2bf(v[0]), f2bf(v[1]), f2bf(v[2]), f2bf(v[3]) };
                *(s16x4*)&Qg[(size_t)tok * D_ + fb] = o;
            } else if (nt < 8) {
                s16x4 o = { f2bf(v[0]), f2bf(v[1]), f2bf(v[2]), f2bf(v[3]) };
                *(s16x4*)&Kg[(size_t)tok * D_ + fb] = o;
            } else {
                const int lt = h * 16 + l15;
                #pragma unroll
                for (int r = 0; r < 4; ++r)
                    sVT[(fb + r) * 72 + lt] = f2bf(v[r]);
            }
        }
    }
    __syncthreads();
    {   // cooperative transposed V store: 64 features x 64 tokens, 32B/thread
        const int d  = tid >> 2;
        const int tq = (tid & 3) * 16;
        s16x8 v0 = *(const s16x8*)&sVT[d * 72 + tq];
        s16x8 v1 = *(const s16x8*)&sVT[d * 72 + tq + 8];
        short* pout = &VTg[(size_t)(bb * D_ + d) * T_ + (t0 & (T_ - 1)) + tq];
        *(s16x8*)pout = v0;
        *(s16x8*)(pout + 8) = v1;
    }
}

// ---------------------------------------------------------------------------
// Kernel 2: causal flash attention, split-K, with next-chunk K/V register
// prefetch (R5 dropped it; restored — removes per-chunk vmcnt stall).
// ---------------------------------------------------------------------------
__global__ __launch_bounds__(256, 4) void attn_kernel(
    const short* __restrict__ Qg, const short* __restrict__ Kg,
    const short* __restrict__ VTg, float* __restrict__ out)
{
    __shared__ char smem[20736];
    short* sP = (short*)smem;                   // [4][16*72] bf16 (loop phase)
    float* sO = (float*)smem;                   // [4][64][20] fp32 (merge, union)
    float* sl = (float*)(smem + 20480);         // [4][16]

    const int tid  = threadIdx.x;
    const int lane = tid & 63;
    const int w    = tid >> 6;
    const int l15  = lane & 15, quad = lane >> 4;
    const int b    = blockIdx.x & 7;
    const int j    = 127 - (blockIdx.x >> 3);   // longest-first
    const int tq0  = j * 16;
    const int nch  = (j >> 2) + 1;
    const int seg  = (nch + 3) >> 2;
    const int c0   = w * seg;
    const int c1   = (c0 + seg < nch) ? c0 + seg : nch;

    const size_t qoff = ((size_t)b * T_ + tq0 + l15) * D_ + quad * 8;
    const s16x8 aq0 = *(const s16x8*)&Qg[qoff];        // pre-scaled by 1/8
    const s16x8 aq1 = *(const s16x8*)&Qg[qoff + 32];

    f32x4 oacc[4];
    float lpart[4] = {0.f, 0.f, 0.f, 0.f};
    #pragma unroll
    for (int nt = 0; nt < 4; ++nt) oacc[nt] = (f32x4){0.f, 0.f, 0.f, 0.f};

    const short* kb = Kg  + (size_t)b * T_ * D_;
    const short* vb = VTg + (size_t)b * D_ * T_;
    short* sPw = sP + w * (16 * 72);

    // initial frags (idle waves clamp to a harmless valid chunk)
    const int cini = (c0 < nch) ? c0 : nch - 1;
    s16x8 bk[4][2], bv[4][2];
    #pragma unroll
    for (int nt = 0; nt < 4; ++nt) {
        const short* pk = kb + (size_t)(cini * 64 + nt * 16 + l15) * D_ + quad * 8;
        bk[nt][0] = *(const s16x8*)pk;
        bk[nt][1] = *(const s16x8*)(pk + 32);
        const short* pv = vb + (size_t)(nt * 16 + l15) * T_ + cini * 64 + quad * 8;
        bv[nt][0] = *(const s16x8*)pv;
        bv[nt][1] = *(const s16x8*)(pv + 32);
    }

    for (int c = c0; c < c1; ++c) {
        const int s0 = c * 64;
        const int sn = (c + 1 < c1 ? c + 1 : c) * 64;

        // ---- prefetch next chunk's K/V frags (in flight during compute)
        s16x8 nk[4][2], nv[4][2];
        #pragma unroll
        for (int nt = 0; nt < 4; ++nt) {
            const short* pk = kb + (size_t)(sn + nt * 16 + l15) * D_ + quad * 8;
            nk[nt][0] = *(const s16x8*)pk;
            nk[nt][1] = *(const s16x8*)(pk + 32);
            const short* pv = vb + (size_t)(nt * 16 + l15) * T_ + sn + quad * 8;
            nv[nt][0] = *(const s16x8*)pv;
            nv[nt][1] = *(const s16x8*)(pv + 32);
        }

        // ---- S = Q K^T
        const f32x4 zz = (f32x4){0.f, 0.f, 0.f, 0.f};
        f32x4 sacc[4];
        #pragma unroll
        for (int nt = 0; nt < 4; ++nt) {
            sacc[nt] = MFMA16(aq0, bk[nt][0], zz);
            sacc[nt] = MFMA16(aq1, bk[nt][1], sacc[nt]);
        }

        // ---- p = exp(s); causal zero on diagonal chunk; in-lane l partial
        const bool diag = (c == nch - 1);
        float p[4][4];
        #pragma unroll
        for (int nt = 0; nt < 4; ++nt)
            #pragma unroll
            for (int r = 0; r < 4; ++r) {
                float e = __expf(sacc[nt][r]);
                if (diag && (s0 + nt * 16 + l15 > tq0 + quad * 4 + r)) e = 0.f;
                p[nt][r] = e;
            }
        #pragma unroll
        for (int r = 0; r < 4; ++r)
            lpart[r] += (p[0][r] + p[1][r]) + (p[2][r] + p[3][r]);

        // ---- P: C-layout -> LDS -> A-layout (wave-private, no barrier)
        #pragma unroll
        for (int nt = 0; nt < 4; ++nt)
            #pragma unroll
            for (int r = 0; r < 4; ++r)
                sPw[(quad * 4 + r) * 72 + nt * 16 + l15] = f2bf(p[nt][r]);
        s16x8 ap0 = *(const s16x8*)&sPw[l15 * 72 + quad * 8];
        s16x8 ap1 = *(const s16x8*)&sPw[l15 * 72 + 32 + quad * 8];

        // ---- O += P V
        #pragma unroll
        for (int nt = 0; nt < 4; ++nt) {
            oacc[nt] = MFMA16(ap0, bv[nt][0], oacc[nt]);
            oacc[nt] = MFMA16(ap1, bv[nt][1], oacc[nt]);
        }

        #pragma unroll
        for (int nt = 0; nt < 4; ++nt) {
            bk[nt][0] = nk[nt][0]; bk[nt][1] = nk[nt][1];
            bv[nt][0] = nv[nt][0]; bv[nt][1] = nv[nt][1];
        }
    }

    // ---- per-wave l reduction (once per strip, not per chunk)
    f32x4 lv;
    #pragma unroll
    for (int r = 0; r < 4; ++r) lv[r] = rsum16(lpart[r]);

    __syncthreads();                            // all waves done with sP
    float* sOw = sO + w * (64 * 20);
    #pragma unroll
    for (int nt = 0; nt < 4; ++nt)
        *(f32x4*)&sOw[(nt * 16 + l15) * 20 + quad * 4] = oacc[nt];
    if (l15 == 0)
        *(f32x4*)&sl[w * 16 + quad * 4] = lv;
    __syncthreads();

    // ---- merge: 256 threads, each 4 rows x 1 dim
    const int d  = tid & 63;
    const int rb = (tid >> 6) * 4;
    f32x4 osum = (f32x4){0.f, 0.f, 0.f, 0.f};
    f32x4 lsum = (f32x4){0.f, 0.f, 0.f, 0.f};
    #pragma unroll
    for (int w2 = 0; w2 < 4; ++w2) {
        osum += *(const f32x4*)&sO[w2 * (64 * 20) + d * 20 + rb];
        lsum += *(const f32x4*)&sl[w2 * 16 + rb];
    }
    #pragma unroll
    for (int i = 0; i < 4; ++i)
        out[((size_t)b * T_ + tq0 + rb + i) * D_ + d] = osum[i] / lsum[i];
}

extern "C" void kernel_launch(void* const* d_in, const int* in_sizes, int n_in,
                              void* d_out, int out_size, void* d_ws, size_t ws_size,
                              hipStream_t stream) {
    (void)in_sizes; (void)n_in; (void)out_size; (void)ws_size;
    const float* x  = (const float*)d_in[0];
    const float* Wq = (const float*)d_in[1];
    const float* bq = (const float*)d_in[2];
    const float* Wk = (const float*)d_in[3];
    const float* bk = (const float*)d_in[4];
    const float* Wv = (const float*)d_in[5];
    const float* bv = (const float*)d_in[6];

    char* ws = (char*)d_ws;
    short* Qg  = (short*)(ws);                           // [BT][64] bf16, 2 MB
    short* Kg  = (short*)(ws + (size_t)2 * 1024 * 1024);
    short* VTg = (short*)(ws + (size_t)4 * 1024 * 1024); // [B][64][T] bf16
    short* Wt  = (short*)(ws + (size_t)6 * 1024 * 1024); // [192][1024] bf16

    wtrans_kernel<<<48, 256, 0, stream>>>(Wq, Wk, Wv, Wt);
    qkv_kernel<<<BT_ / 64, 256, 0, stream>>>(x, Wt, bq, bk, bv, Qg, Kg, VTg);
    attn_kernel<<<B_ * 128, 256, 0, stream>>>(Qg, Kg, VTg, (float*)d_out);
}

// Round 8
// 159.202 us; speedup vs baseline: 1.1356x; 1.1356x over previous
//
#include <hip/hip_runtime.h>
#include <math.h>

// Single-head causal attention, B=8 T=2048 E=1024 D=64, fp32 in/out.
// wtrans (W -> bf16 W^T) -> qkv (MFMA GEMM, 32 tok/block, 2-deep x pipeline)
// -> attn (flash attention, split-K, strip-pairing for uniform block work).

#define B_   8
#define T_   2048
#define E_   1024
#define D_   64
#define BT_  (B_ * T_)

typedef __attribute__((ext_vector_type(8))) short s16x8;   // 8 x bf16
typedef __attribute__((ext_vector_type(4))) short s16x4;
typedef __attribute__((ext_vector_type(4))) float f32x4;

__device__ __forceinline__ short f2bf(float f) {
    union { float f; unsigned u; } a; a.f = f;
    unsigned r = a.u + 0x7fffu + ((a.u >> 16) & 1u);   // RNE
    return (short)(r >> 16);
}

#define MFMA16(a, b, c) __builtin_amdgcn_mfma_f32_16x16x32_bf16((a), (b), (c), 0, 0, 0)

// DPP cross-lane move within 16-lane rows (VALU pipe, not DS).
#define DPPF(x, ctrl) __builtin_bit_cast(float, \
    __builtin_amdgcn_update_dpp(0, __builtin_bit_cast(int, (x)), (ctrl), 0xF, 0xF, true))

__device__ __forceinline__ float rsum16(float x) {
    x += DPPF(x, 0xB1);     // quad_perm xor1
    x += DPPF(x, 0x4E);     // quad_perm xor2
    x += DPPF(x, 0x124);    // row_ror:4
    x += DPPF(x, 0x128);    // row_ror:8
    return x;
}

// ---------------------------------------------------------------------------
// Kernel 0: W[1024][64] x3 (fp32) -> Wt[192][1024] (bf16, K-major).
// ---------------------------------------------------------------------------
__global__ __launch_bounds__(256) void wtrans_kernel(
    const float* __restrict__ Wq, const float* __restrict__ Wk,
    const float* __restrict__ Wv, short* __restrict__ Wt)
{
    __shared__ float sT[64][65];
    const int sel = blockIdx.x >> 4;            // 0=q 1=k 2=v
    const int k0  = (blockIdx.x & 15) * 64;
    const float* W = sel == 0 ? Wq : (sel == 1 ? Wk : Wv);
    const int t  = threadIdx.x;
    const int kr = t >> 4, c4 = (t & 15) * 4;
    #pragma unroll
    for (int i = 0; i < 4; ++i) {
        float4 v = *(const float4*)&W[(size_t)(k0 + kr + i * 16) * D_ + c4];
        sT[kr + i * 16][c4 + 0] = v.x; sT[kr + i * 16][c4 + 1] = v.y;
        sT[kr + i * 16][c4 + 2] = v.z; sT[kr + i * 16][c4 + 3] = v.w;
    }
    __syncthreads();
    #pragma unroll
    for (int i = 0; i < 4; ++i) {
        int n  = (t >> 4) + i * 16;
        int kk = (t & 15) * 4;
        s16x4 o;
        o.x = f2bf(sT[kk + 0][n]); o.y = f2bf(sT[kk + 1][n]);
        o.z = f2bf(sT[kk + 2][n]); o.w = f2bf(sT[kk + 3][n]);
        *(s16x4*)&Wt[(size_t)(sel * 64 + n) * E_ + k0 + kk] = o;
    }
}

// ---------------------------------------------------------------------------
// Kernel 1: QKV projection. Block 256 = 4 waves, 32 tokens, grid 512
// (2 blocks/CU). x loads pipelined 2 iterations deep (~500 cyc of cover).
// ---------------------------------------------------------------------------
__global__ __launch_bounds__(256) void qkv_kernel(
    const float* __restrict__ x, const short* __restrict__ Wt,
    const float* __restrict__ bq, const float* __restrict__ bk,
    const float* __restrict__ bv,
    short* __restrict__ Qg, short* __restrict__ Kg, short* __restrict__ VTg)
{
    __shared__ short sX[2][32 * 76];            // [buf][token][64+12 pad] bf16
    const int tid  = threadIdx.x;
    const int lane = tid & 63;
    const int w    = tid >> 6;
    const int l15  = lane & 15, quad = lane >> 4;
    const int t0   = blockIdx.x * 32;
    const int bb   = t0 >> 11;                  // batch (blocks don't straddle)

    const int srow = tid >> 3;                  // 0..31
    const int skc  = (tid & 7) * 8;             // 0..56
    const float* px = &x[(size_t)(t0 + srow) * E_ + skc];

    f32x4 acc[3][2];
    #pragma unroll
    for (int a = 0; a < 3; ++a)
        #pragma unroll
        for (int h = 0; h < 2; ++h)
            acc[a][h] = (f32x4){0.f, 0.f, 0.f, 0.f};

    float4 lda0 = *(const float4*)px;                 // k0 = 0
    float4 lda1 = *(const float4*)(px + 4);
    float4 ldb0 = *(const float4*)(px + 64);          // k0 = 64
    float4 ldb1 = *(const float4*)(px + 68);

    int buf = 0;
    for (int k0 = 0; k0 < E_; k0 += 64) {
        s16x8 pk;
        pk[0] = f2bf(lda0.x); pk[1] = f2bf(lda0.y);
        pk[2] = f2bf(lda0.z); pk[3] = f2bf(lda0.w);
        pk[4] = f2bf(lda1.x); pk[5] = f2bf(lda1.y);
        pk[6] = f2bf(lda1.z); pk[7] = f2bf(lda1.w);
        *(s16x8*)&sX[buf][srow * 76 + skc] = pk;
        __syncthreads();

        lda0 = ldb0; lda1 = ldb1;               // shift 2-deep pipeline
        if (k0 + 128 < E_) {
            const float* p2 = px + k0 + 128;
            ldb0 = *(const float4*)p2;
            ldb1 = *(const float4*)(p2 + 4);
        }

        s16x8 aw[3][2];
        #pragma unroll
        for (int t3 = 0; t3 < 3; ++t3) {
            const short* pw = &Wt[(size_t)((w * 3 + t3) * 16 + l15) * E_ + k0 + quad * 8];
            aw[t3][0] = *(const s16x8*)pw;
            aw[t3][1] = *(const s16x8*)(pw + 32);
        }
        s16x8 bxf[2][2];
        #pragma unroll
        for (int h = 0; h < 2; ++h) {
            bxf[h][0] = *(const s16x8*)&sX[buf][(h * 16 + l15) * 76 + quad * 8];
            bxf[h][1] = *(const s16x8*)&sX[buf][(h * 16 + l15) * 76 + 32 + quad * 8];
        }
        #pragma unroll
        for (int t3 = 0; t3 < 3; ++t3)
            #pragma unroll
            for (int h = 0; h < 2; ++h) {
                acc[t3][h] = MFMA16(aw[t3][0], bxf[h][0], acc[t3][h]);
                acc[t3][h] = MFMA16(aw[t3][1], bxf[h][1], acc[t3][h]);
            }
        buf ^= 1;
    }

    __syncthreads();                            // main-loop LDS reads done
    short* sVT = &sX[0][0];                     // overlay: [64 feat][48 tok pad]

    #pragma unroll
    for (int t3 = 0; t3 < 3; ++t3) {
        const int nt = w * 3 + t3;
        const int fb = (nt & 3) * 16 + quad * 4;
        const float* bias = nt < 4 ? bq : (nt < 8 ? bk : bv);
        f32x4 bsv = *(const f32x4*)&bias[fb];
        #pragma unroll
        for (int h = 0; h < 2; ++h) {
            const int tok = t0 + h * 16 + l15;
            f32x4 v = acc[t3][h] + bsv;
            if (nt < 4) {
                v *= 0.125f;                    // fold 1/sqrt(64) into Q
                s16x4 o = { f2bf(v[0]), f2bf(v[1]), f2bf(v[2]), f2bf(v[3]) };
                *(s16x4*)&Qg[(size_t)tok * D_ + fb] = o;
            } else if (nt < 8) {
                s16x4 o = { f2bf(v[0]), f2bf(v[1]), f2bf(v[2]), f2bf(v[3]) };
                *(s16x4*)&Kg[(size_t)tok * D_ + fb] = o;
            } else {
                const int lt = h * 16 + l15;
                #pragma unroll
                for (int r = 0; r < 4; ++r)
                    sVT[(fb + r) * 48 + lt] = f2bf(v[r]);
            }
        }
    }
    __syncthreads();
    {   // cooperative transposed V store: 64 features x 32 tokens, 16B/lane
        const int d  = tid >> 2;
        const int tq = (tid & 3) * 8;
        s16x8 vv = *(const s16x8*)&sVT[d * 48 + tq];
        *(s16x8*)&VTg[(size_t)(bb * D_ + d) * T_ + (t0 & (T_ - 1)) + tq] = vv;
    }
}

// ---------------------------------------------------------------------------
// Kernel 2: causal flash attention, split-K with STRIP PAIRING.
// Block = 4 waves handles strips jA = pair and jB = 127-pair; total chunks
// nchA+nchB = 32..33 for every block -> uniform work, no tail. The 4 waves
// split the concatenated chunk list; partials merge per strip via LDS.
// No launch-bounds cap, no register prefetch (R7 post-mortem: spills).
// ---------------------------------------------------------------------------
__global__ __launch_bounds__(256) void attn_kernel(
    const short* __restrict__ Qg, const short* __restrict__ Kg,
    const short* __restrict__ VTg, float* __restrict__ out)
{
    __shared__ char smem[20736];
    short* sP = (short*)smem;                   // [4][16*72] bf16 (loop phase)
    float* sO = (float*)smem;                   // [4][64][20] fp32 (merge, union)
    float* sl = (float*)(smem + 20480);         // [4][16]

    const int tid  = threadIdx.x;
    const int lane = tid & 63;
    const int w    = tid >> 6;
    const int l15  = lane & 15, quad = lane >> 4;
    const int b    = blockIdx.x & 7;
    const int pr   = blockIdx.x >> 3;           // 0..63
    const int jA   = pr, jB = 127 - pr;
    const int tqA  = jA * 16, tqB = jB * 16;
    const int nchA = (jA >> 2) + 1, nchB = (jB >> 2) + 1;
    const int tot  = nchA + nchB;               // 32 or 33
    const int seg  = (tot + 3) >> 2;
    const int c0   = w * seg;
    const int c1   = (c0 + seg < tot) ? c0 + seg : tot;

    const size_t qoffA = ((size_t)b * T_ + tqA + l15) * D_ + quad * 8;
    const s16x8 aqA0 = *(const s16x8*)&Qg[qoffA];      // pre-scaled by 1/8
    const s16x8 aqA1 = *(const s16x8*)&Qg[qoffA + 32];
    const size_t qoffB = ((size_t)b * T_ + tqB + l15) * D_ + quad * 8;
    const s16x8 aqB0 = *(const s16x8*)&Qg[qoffB];
    const s16x8 aqB1 = *(const s16x8*)&Qg[qoffB + 32];

    f32x4 oA[4], oB[4];
    float lA[4] = {0.f, 0.f, 0.f, 0.f}, lB[4] = {0.f, 0.f, 0.f, 0.f};
    #pragma unroll
    for (int nt = 0; nt < 4; ++nt) {
        oA[nt] = (f32x4){0.f, 0.f, 0.f, 0.f};
        oB[nt] = (f32x4){0.f, 0.f, 0.f, 0.f};
    }

    const short* kb = Kg  + (size_t)b * T_ * D_;
    const short* vb = VTg + (size_t)b * D_ * T_;
    short* sPw = sP + w * (16 * 72);

    // one chunk of one strip: QK -> exp -> LDS transform -> PV
    auto body = [&](int cc, int tq, int nch, const s16x8& q0, const s16x8& q1,
                    f32x4 (&oo)[4], float (&lp)[4]) {
        const int s0 = cc * 64;
        s16x8 bk[4][2];
        #pragma unroll
        for (int nt = 0; nt < 4; ++nt) {
            const short* pk = kb + (size_t)(s0 + nt * 16 + l15) * D_ + quad * 8;
            bk[nt][0] = *(const s16x8*)pk;
            bk[nt][1] = *(const s16x8*)(pk + 32);
        }
        const f32x4 zz = (f32x4){0.f, 0.f, 0.f, 0.f};
        f32x4 sacc[4];
        #pragma unroll
        for (int nt = 0; nt < 4; ++nt) {
            sacc[nt] = MFMA16(q0, bk[nt][0], zz);
            sacc[nt] = MFMA16(q1, bk[nt][1], sacc[nt]);
        }
        s16x8 bv[4][2];
        #pragma unroll
        for (int nt = 0; nt < 4; ++nt) {
            const short* pv = vb + (size_t)(nt * 16 + l15) * T_ + s0 + quad * 8;
            bv[nt][0] = *(const s16x8*)pv;
            bv[nt][1] = *(const s16x8*)(pv + 32);
        }
        const bool diag = (cc == nch - 1);
        float p[4][4];
        #pragma unroll
        for (int nt = 0; nt < 4; ++nt)
            #pragma unroll
            for (int r = 0; r < 4; ++r) {
                float e = __expf(sacc[nt][r]);
                if (diag && (s0 + nt * 16 + l15 > tq + quad * 4 + r)) e = 0.f;
                p[nt][r] = e;
            }
        #pragma unroll
        for (int r = 0; r < 4; ++r)
            lp[r] += (p[0][r] + p[1][r]) + (p[2][r] + p[3][r]);
        #pragma unroll
        for (int nt = 0; nt < 4; ++nt)
            #pragma unroll
            for (int r = 0; r < 4; ++r)
                sPw[(quad * 4 + r) * 72 + nt * 16 + l15] = f2bf(p[nt][r]);
        s16x8 ap0 = *(const s16x8*)&sPw[l15 * 72 + quad * 8];
        s16x8 ap1 = *(const s16x8*)&sPw[l15 * 72 + 32 + quad * 8];
        #pragma unroll
        for (int nt = 0; nt < 4; ++nt) {
            oo[nt] = MFMA16(ap0, bv[nt][0], oo[nt]);
            oo[nt] = MFMA16(ap1, bv[nt][1], oo[nt]);
        }
    };

    for (int c = c0; c < c1; ++c) {
        if (c < nchA) body(c, tqA, nchA, aqA0, aqA1, oA, lA);
        else          body(c - nchA, tqB, nchB, aqB0, aqB1, oB, lB);
    }

    f32x4 lvA, lvB;
    #pragma unroll
    for (int r = 0; r < 4; ++r) { lvA[r] = rsum16(lA[r]); lvB[r] = rsum16(lB[r]); }

    const int d  = tid & 63;
    const int rb = (tid >> 6) * 4;

    // ---- merge strip A
    __syncthreads();                            // all waves done with sP
    {
        float* sOw = sO + w * (64 * 20);
        #pragma unroll
        for (int nt = 0; nt < 4; ++nt)
            *(f32x4*)&sOw[(nt * 16 + l15) * 20 + quad * 4] = oA[nt];
        if (l15 == 0) *(f32x4*)&sl[w * 16 + quad * 4] = lvA;
    }
    __syncthreads();
    {
        f32x4 osum = (f32x4){0.f, 0.f, 0.f, 0.f};
        f32x4 lsum = (f32x4){0.f, 0.f, 0.f, 0.f};
        #pragma unroll
        for (int w2 = 0; w2 < 4; ++w2) {
            osum += *(const f32x4*)&sO[w2 * (64 * 20) + d * 20 + rb];
            lsum += *(const f32x4*)&sl[w2 * 16 + rb];
        }
        #pragma unroll
        for (int i = 0; i < 4; ++i)
            out[((size_t)b * T_ + tqA + rb + i) * D_ + d] = osum[i] / lsum[i];
    }

    // ---- merge strip B
    __syncthreads();
    {
        float* sOw = sO + w * (64 * 20);
        #pragma unroll
        for (int nt = 0; nt < 4; ++nt)
            *(f32x4*)&sOw[(nt * 16 + l15) * 20 + quad * 4] = oB[nt];
        if (l15 == 0) *(f32x4*)&sl[w * 16 + quad * 4] = lvB;
    }
    __syncthreads();
    {
        f32x4 osum = (f32x4){0.f, 0.f, 0.f, 0.f};
        f32x4 lsum = (f32x4){0.f, 0.f, 0.f, 0.f};
        #pragma unroll
        for (int w2 = 0; w2 < 4; ++w2) {
            osum += *(const f32x4*)&sO[w2 * (64 * 20) + d * 20 + rb];
            lsum += *(const f32x4*)&sl[w2 * 16 + rb];
        }
        #pragma unroll
        for (int i = 0; i < 4; ++i)
            out[((size_t)b * T_ + tqB + rb + i) * D_ + d] = osum[i] / lsum[i];
    }
}

extern "C" void kernel_launch(void* const* d_in, const int* in_sizes, int n_in,
                              void* d_out, int out_size, void* d_ws, size_t ws_size,
                              hipStream_t stream) {
    (void)in_sizes; (void)n_in; (void)out_size; (void)ws_size;
    const float* x  = (const float*)d_in[0];
    const float* Wq = (const float*)d_in[1];
    const float* bq = (const float*)d_in[2];
    const float* Wk = (const float*)d_in[3];
    const float* bk = (const float*)d_in[4];
    const float* Wv = (const float*)d_in[5];
    const float* bv = (const float*)d_in[6];

    char* ws = (char*)d_ws;
    short* Qg  = (short*)(ws);                           // [BT][64] bf16, 2 MB
    short* Kg  = (short*)(ws + (size_t)2 * 1024 * 1024);
    short* VTg = (short*)(ws + (size_t)4 * 1024 * 1024); // [B][64][T] bf16
    short* Wt  = (short*)(ws + (size_t)6 * 1024 * 1024); // [192][1024] bf16

    wtrans_kernel<<<48, 256, 0, stream>>>(Wq, Wk, Wv, Wt);
    qkv_kernel<<<BT_ / 32, 256, 0, stream>>>(x, Wt, bq, bk, bv, Qg, Kg, VTg);
    attn_kernel<<<B_ * 64, 256, 0, stream>>>(Qg, Kg, VTg, (float*)d_out);
}